// Round 18
// baseline (234.107 us; speedup 1.0000x reference)
//
#include <hip/hip_runtime.h>
#include <hip/hip_fp8.h>

#define DD 128
#define CC 64
#define BKW 512            // nodes per bucket
#define NPB 4096           // edges per phase-B block

typedef __attribute__((ext_vector_type(8))) short short8v;
typedef __attribute__((ext_vector_type(4))) float f32x4;
typedef __attribute__((ext_vector_type(2))) float f32x2;

static __device__ inline ushort f2bf_rne(float f) {
    unsigned u = __float_as_uint(f);
    unsigned r = (u + 0x7FFFu + ((u >> 16) & 1u)) >> 16;
    return (ushort)r;
}
static __device__ inline float bf2f(ushort h) {
    return __uint_as_float(((unsigned)h) << 16);
}
static __device__ inline float bflo(uint u) {
    return __uint_as_float(u << 16);
}
static __device__ inline float bfhi(uint u) {
    return __uint_as_float(u & 0xffff0000u);
}

// ============ bucket histogram: per-block LDS hist, 256 global atomics ======
__global__ __launch_bounds__(256) void bucket_cnt_kernel(const int* __restrict__ ei,
                                                         int* __restrict__ bcnt, int E) {
    __shared__ int h[256];
    const int t = threadIdx.x;
    h[t] = 0;
    __syncthreads();
    const int base = blockIdx.x * 8192;
    const int end = min(E, base + 8192);
    for (int j = base + t; j < end; j += 256) {
        atomicAdd(&h[ei[E + j] >> 9], 1);
    }
    __syncthreads();
    if (h[t]) atomicAdd(&bcnt[t], h[t]);
}

// ============ bucket scan (256 entries, 1 block) -> boffs[257], bcur ========
__global__ __launch_bounds__(256) void bucket_scan_kernel(const int* __restrict__ bcnt,
                                                          int* __restrict__ boffs,
                                                          int* __restrict__ bcur) {
    __shared__ int s[256];
    const int t = threadIdx.x;
    int v = bcnt[t];
    s[t] = v;
    __syncthreads();
    for (int off = 1; off < 256; off <<= 1) {
        int xv = 0;
        if (t >= off) xv = s[t - off];
        __syncthreads();
        if (t >= off) s[t] += xv;
        __syncthreads();
    }
    int excl = s[t] - v;
    boffs[t] = excl;
    bcur[t] = excl;
    if (t == 255) boffs[256] = s[255];
}

// ===== phase B: bin edges by bucket; packed word = src | (dst&511)<<17 ======
// bucket id (0..195, 8 bits) in a separate byte array (R14 lesson).
__global__ __launch_bounds__(256) void binA_kernel(const int* __restrict__ ei,
                                                   int* __restrict__ bcur,
                                                   uint* __restrict__ ebuf, int E) {
    __shared__ int sRun[256];
    __shared__ int sRel[256];
    __shared__ int sBase[256];
    __shared__ uint sPair[NPB];
    __shared__ unsigned char sBkt[NPB];
    __shared__ int sHist[256];
    const int t = threadIdx.x;
    const int e0 = blockIdx.x * NPB;
    const int cntE = min(NPB, E - e0);

    sHist[t] = 0;
    __syncthreads();
    for (int j = t; j < cntE; j += 256) {
        int dst = ei[E + e0 + j];
        atomicAdd(&sHist[dst >> 9], 1);
    }
    __syncthreads();
    int h = sHist[t];
    sRun[t] = h;
    __syncthreads();
    for (int off = 1; off < 256; off <<= 1) {
        int v = 0;
        if (t >= off) v = sRun[t - off];
        __syncthreads();
        if (t >= off) sRun[t] += v;
        __syncthreads();
    }
    int runstart = sRun[t] - h;
    int base = 0;
    if (h > 0) base = atomicAdd(&bcur[t], h);
    sRun[t] = runstart;
    sRel[t] = runstart;
    sBase[t] = base;
    __syncthreads();
    for (int j = t; j < cntE; j += 256) {
        int src = ei[e0 + j];
        int dst = ei[E + e0 + j];
        int b = dst >> 9;
        int slot = atomicAdd(&sRel[b], 1);
        sPair[slot] = (uint)src | ((uint)(dst & 511) << 17);
        sBkt[slot] = (unsigned char)b;
    }
    __syncthreads();
    for (int s = t; s < cntE; s += 256) {
        uint p = sPair[s];
        int b = (int)sBkt[s];
        int gpos = sBase[b] + (s - sRun[b]);
        ebuf[gpos] = p;
    }
}

// ====== phase C: per-bucket: derive per-node offs in LDS, then scatter =====
__global__ __launch_bounds__(256) void binB2_kernel(const uint* __restrict__ ebuf,
                                                    const int* __restrict__ boffs,
                                                    int* __restrict__ offs,
                                                    int* __restrict__ csr, int n) {
    __shared__ int sCnt[BKW];
    __shared__ int sOffs[BKW];
    __shared__ int sScan[256];
    const int t = threadIdx.x;
    const int node0 = blockIdx.x * BKW;
    const int node1 = min(n, node0 + BKW);
    const int start = boffs[blockIdx.x];
    const int end = boffs[blockIdx.x + 1];

    sCnt[t] = 0; sCnt[t + 256] = 0;
    __syncthreads();
    for (int j = start + t; j < end; j += 256) {
        int d = (int)(ebuf[j] >> 17);
        atomicAdd(&sCnt[d], 1);
    }
    __syncthreads();
    int v0 = sCnt[2 * t], v1 = sCnt[2 * t + 1];
    int sum = v0 + v1;
    sScan[t] = sum;
    __syncthreads();
    for (int off = 1; off < 256; off <<= 1) {
        int xv = 0;
        if (t >= off) xv = sScan[t - off];
        __syncthreads();
        if (t >= off) sScan[t] += xv;
        __syncthreads();
    }
    int excl = sScan[t] - sum;
    sOffs[2 * t] = start + excl;
    sOffs[2 * t + 1] = start + excl + v0;
    __syncthreads();
    for (int i = t; i < BKW; i += 256) {
        int node = node0 + i;
        if (node < n) offs[node] = sOffs[i];
    }
    if (node1 == n && t == 0) offs[n] = end;
    __syncthreads();
    sCnt[t] = 0; sCnt[t + 256] = 0;
    __syncthreads();
    for (int j = start + t; j < end; j += 256) {
        uint p = ebuf[j];
        int d = (int)(p >> 17);
        int r = atomicAdd(&sCnt[d], 1);
        csr[sOffs[d] + r] = (int)(p & 0x1FFFFu);
    }
}

// ===== merged prep: x -> (xh bf16, xq e4m3) + wfrag + wofrag ===============
__global__ __launch_bounds__(256) void prep_kernel(
    const float* __restrict__ x, ushort* __restrict__ xh, uint* __restrict__ xq,
    const float* __restrict__ Wl1, const float* __restrict__ Wr1,
    const float* __restrict__ Wl2, const float* __restrict__ Wr2,
    const float* __restrict__ Wout,
    ushort* __restrict__ WTfrag1, ushort* __restrict__ WTfrag2,
    ushort* __restrict__ WoFrag, int nxblk) {
    const int t = threadIdx.x;
    const int bx = blockIdx.x;
    if (bx < nxblk) {
        int i = bx * 256 + t;                    // 8 elems per thread
        float4 a = ((const float4*)x)[2 * i];
        float4 b = ((const float4*)x)[2 * i + 1];
        float vv[8] = {a.x, a.y, a.z, a.w, b.x, b.y, b.z, b.w};
        ushort r[8];
        uint q[8];
        #pragma unroll
        for (int j = 0; j < 8; ++j) {
            r[j] = f2bf_rne(vv[j]);
            q[j] = (uint)__hip_fp8_e4m3(vv[j]).__x;
        }
        uint4 o;
        o.x = (uint)r[0] | ((uint)r[1] << 16);
        o.y = (uint)r[2] | ((uint)r[3] << 16);
        o.z = (uint)r[4] | ((uint)r[5] << 16);
        o.w = (uint)r[6] | ((uint)r[7] << 16);
        ((uint4*)xh)[i] = o;
        uint2 oq;
        oq.x = q[0] | (q[1] << 8) | (q[2] << 16) | (q[3] << 24);
        oq.y = q[4] | (q[5] << 8) | (q[6] << 16) | (q[7] << 24);
        ((uint2*)xq)[i] = oq;
    } else if (bx < nxblk + 32) {
        int li = bx - nxblk;
        int layer = li >> 4;
        int idx = (li & 15) * 256 + t;           // [0, 4096)
        const float* Wl = layer ? Wl2 : Wl1;
        const float* Wr = layer ? Wr2 : Wr1;
        ushort* dst = (layer ? WTfrag2 : WTfrag1) + (size_t)idx * 8;
        int lane = idx & 63, tt = (idx >> 6) & 7, s = idx >> 9;
        int col = tt * 16 + (lane & 15);
        int k0 = s * 32 + (lane >> 4) * 8;
        #pragma unroll
        for (int j = 0; j < 8; ++j) {
            int k = k0 + j;
            float v = (k < DD) ? Wl[k * DD + col] : Wr[(k - DD) * DD + col];
            dst[j] = f2bf_rne(v);
        }
    } else {
        int idx = (bx - nxblk - 32) * 256 + t;   // [0, 1024)
        ushort* dst = WoFrag + (size_t)idx * 8;
        int lane = idx & 63, tt = (idx >> 6) & 3, kc = idx >> 8;
        int col = tt * 16 + (lane & 15);
        int k0 = kc * 32 + (lane >> 4) * 8;
        #pragma unroll
        for (int j = 0; j < 8; ++j) {
            dst[j] = f2bf_rne(Wout[(k0 + j) * CC + col]);
        }
    }
}

// ====== CSR gather-aggregate, fp8 rows: 16 nbrs in flight ====
__global__ __launch_bounds__(256) void csr_agg8_kernel(
    const uint* __restrict__ xq, const int* __restrict__ offs,
    const int* __restrict__ csr, ushort* __restrict__ meanH, int n) {
    int node = blockIdx.x * 4 + (threadIdx.x >> 6);
    if (node >= n) return;
    const int lane = threadIdx.x & 63;
    const int sub = lane >> 4;
    const int li = lane & 15;
    const int start = offs[node];
    const int c = offs[node + 1] - start;
    f32x2 a[4], aa[4];
    #pragma unroll
    for (int k = 0; k < 4; ++k) { a[k] = (f32x2){0.f, 0.f}; aa[k] = (f32x2){0.f, 0.f}; }
    #define ACC8(A, U) { \
        A[0] += __builtin_amdgcn_cvt_pk_f32_fp8(U.x, false); \
        A[1] += __builtin_amdgcn_cvt_pk_f32_fp8(U.x, true);  \
        A[2] += __builtin_amdgcn_cvt_pk_f32_fp8(U.y, false); \
        A[3] += __builtin_amdgcn_cvt_pk_f32_fp8(U.y, true);  }
    const int c16 = c & ~15;
    int j = 0;
    if (c16 > 0) {
        int s0 = csr[start + sub];
        int s1 = csr[start + 4 + sub];
        int s2 = csr[start + 8 + sub];
        int s3 = csr[start + 12 + sub];
        for (; j < c16; j += 16) {
            int t0 = 0, t1 = 0, t2 = 0, t3 = 0;
            if (j + 16 < c16) {
                t0 = csr[start + j + 16 + sub];
                t1 = csr[start + j + 20 + sub];
                t2 = csr[start + j + 24 + sub];
                t3 = csr[start + j + 28 + sub];
            }
            uint2 u0 = *(const uint2*)((const uchar*)xq + (size_t)s0 * DD + li * 8);
            uint2 u1 = *(const uint2*)((const uchar*)xq + (size_t)s1 * DD + li * 8);
            uint2 u2 = *(const uint2*)((const uchar*)xq + (size_t)s2 * DD + li * 8);
            uint2 u3 = *(const uint2*)((const uchar*)xq + (size_t)s3 * DD + li * 8);
            ACC8(a, u0); ACC8(a, u1); ACC8(aa, u2); ACC8(aa, u3);
            s0 = t0; s1 = t1; s2 = t2; s3 = t3;
        }
    }
    if (c - j >= 8) {
        int s0 = csr[start + j + sub];
        int s1 = csr[start + j + 4 + sub];
        uint2 u0 = *(const uint2*)((const uchar*)xq + (size_t)s0 * DD + li * 8);
        uint2 u1 = *(const uint2*)((const uchar*)xq + (size_t)s1 * DD + li * 8);
        ACC8(a, u0); ACC8(aa, u1);
        j += 8;
    }
    if (c - j >= 4) {
        int s = csr[start + j + sub];
        uint2 u = *(const uint2*)((const uchar*)xq + (size_t)s * DD + li * 8);
        ACC8(a, u);
        j += 4;
    }
    if (j + sub < c) {
        int s = csr[start + j + sub];
        uint2 u = *(const uint2*)((const uchar*)xq + (size_t)s * DD + li * 8);
        ACC8(aa, u);
    }
    #undef ACC8
    float res[8];
    #pragma unroll
    for (int k = 0; k < 4; ++k) {
        f32x2 v = a[k] + aa[k];
        float e0 = v.x; e0 += __shfl_xor(e0, 16); e0 += __shfl_xor(e0, 32);
        float e1 = v.y; e1 += __shfl_xor(e1, 16); e1 += __shfl_xor(e1, 32);
        res[2 * k] = e0; res[2 * k + 1] = e1;
    }
    if (sub == 0) {
        float inv = 1.0f / fmaxf((float)c, 1.0f);
        short8v o;
        #pragma unroll
        for (int k = 0; k < 8; ++k) o[k] = (short)f2bf_rne(res[k] * inv);
        *(short8v*)(meanH + (size_t)node * DD + li * 8) = o;
    }
}

// ===== MFMA SAGE layer: 256 thr / 64 rows / B-frags direct from global ======
// R13 structure (measured ~26 us): no LDS/barriers in main loop; B-frag loads
// are coalesced 1KB wave reads of a 64KB L1/L2-hot table shared by all blocks.
// !PROJ: dual-write h1 as bf16 + packed e4m3. PROJ: 17KB sH transpose, 1 bar.
template <bool PROJ>
__global__ __launch_bounds__(256) void layer_mfma_kernel(
    const ushort* __restrict__ meanH, const ushort* __restrict__ rootH,
    const ushort* __restrict__ WTfrag, const float* __restrict__ bias,
    ushort* __restrict__ outH, uchar* __restrict__ outQ,
    const ushort* __restrict__ WoFrag, const float* __restrict__ bout,
    float* __restrict__ outF, int n) {
    __shared__ ushort sH[PROJ ? 64 : 1][136];    // stride 272B: 2-way max aliasing
    const int tid = threadIdx.x;
    const int w = tid >> 6;
    const int l = tid & 63;
    const int row0 = blockIdx.x * 64;
    const int lrow = w * 16 + (l & 15);
    const int kb = (l >> 4) * 8;
    const int lcol = l & 15;
    const int arowg = min(row0 + lrow, n - 1);

    const ushort* Am = meanH + (size_t)arowg * DD;
    const ushort* Ar = rootH + (size_t)arowg * DD;

    short8v ap[8];
    #pragma unroll
    for (int s = 0; s < 8; ++s) {
        ap[s] = (s < 4) ? *(const short8v*)(Am + s * 32 + kb)
                        : *(const short8v*)(Ar + (s - 4) * 32 + kb);
    }

    f32x4 acc[8];
    #pragma unroll
    for (int t = 0; t < 8; ++t) acc[t] = (f32x4){0.f, 0.f, 0.f, 0.f};

    #pragma unroll
    for (int s = 0; s < 8; ++s) {
        const ushort* fb = WTfrag + (size_t)s * 4096 + l * 8;
        #pragma unroll
        for (int t = 0; t < 8; ++t) {
            short8v bh = *(const short8v*)(fb + t * 512);
            acc[t] = __builtin_amdgcn_mfma_f32_16x16x32_bf16(ap[s], bh, acc[t], 0, 0, 0);
        }
    }

    // C/D layout: col = t*16 + (lane&15), row = w*16 + 4*(lane>>4) + reg
    const int lrow0 = w * 16 + (l >> 4) * 4;
    if (!PROJ) {
        #pragma unroll
        for (int t = 0; t < 8; ++t) {
            const int col = t * 16 + lcol;
            const float b = bias[col];
            #pragma unroll
            for (int r = 0; r < 4; ++r) {
                int row = row0 + lrow0 + r;
                if (row < n) {
                    float o = fmaxf(acc[t][r] + b, 0.f);
                    outH[(size_t)row * DD + col] = f2bf_rne(o);
                    outQ[(size_t)row * DD + col] = __hip_fp8_e4m3(o).__x;
                }
            }
        }
    } else {
        // wave-local transpose of h2 through sH (wave writes+reads only its rows)
        #pragma unroll
        for (int t = 0; t < 8; ++t) {
            const int col = t * 16 + lcol;
            const float b = bias[col];
            #pragma unroll
            for (int r = 0; r < 4; ++r) {
                sH[lrow0 + r][col] = f2bf_rne(fmaxf(acc[t][r] + b, 0.f));
            }
        }
        __syncthreads();
        f32x4 po[4];
        #pragma unroll
        for (int t = 0; t < 4; ++t) po[t] = (f32x4){0.f, 0.f, 0.f, 0.f};
        #pragma unroll
        for (int kc = 0; kc < 4; ++kc) {
            short8v ah = *(const short8v*)&sH[lrow][kc * 32 + kb];
            const ushort* fb = WoFrag + (size_t)kc * 2048 + l * 8;
            #pragma unroll
            for (int t = 0; t < 4; ++t) {
                short8v bh = *(const short8v*)(fb + t * 512);
                po[t] = __builtin_amdgcn_mfma_f32_16x16x32_bf16(ah, bh, po[t], 0, 0, 0);
            }
        }
        #pragma unroll
        for (int t = 0; t < 4; ++t) {
            const int col = t * 16 + lcol;
            const float b = bout[col];
            #pragma unroll
            for (int r = 0; r < 4; ++r) {
                int row = row0 + lrow0 + r;
                if (row < n) outF[(size_t)row * CC + col] = po[t][r] + b;
            }
        }
    }
}

extern "C" void kernel_launch(void* const* d_in, const int* in_sizes, int n_in,
                              void* d_out, int out_size, void* d_ws, size_t ws_size,
                              hipStream_t stream) {
    const float* x    = (const float*)d_in[0];
    const int*   ei   = (const int*)d_in[1];
    const float* W1l  = (const float*)d_in[2];
    const float* b1   = (const float*)d_in[3];
    const float* W1r  = (const float*)d_in[4];
    const float* W2l  = (const float*)d_in[5];
    const float* b2   = (const float*)d_in[6];
    const float* W2r  = (const float*)d_in[7];
    const float* Wout = (const float*)d_in[8];
    const float* bout = (const float*)d_in[9];
    float* out = (float*)d_out;
    const int n = in_sizes[0] / DD;       // 100000
    const int E = in_sizes[1] / 2;        // 1600000
    const size_t NP = (size_t)n * DD;

    const int NBUCK = (n + BKW - 1) / BKW;

    // workspace (~110 MB); ebuf (6.4MB) aliases the front of xq (12.8MB):
    // ebuf is dead after binB2; prep (which writes xq) runs after binB2.
    int* offs  = (int*)d_ws;                              // 100352 (incl offs[n])
    int* bcnt  = offs + 100352;                           // 256
    int* boffs = bcnt + 256;                              // 257 (pad 512)
    int* bcur  = boffs + 512;                             // 256
    int* csr   = bcur + 256;                              // E (pad)
    uint* ebuf = (uint*)(csr + 1600256);                  // E packed words
    uint* xq   = ebuf;                                    // n*128 fp8 (12.8MB)
    ushort* xh = (ushort*)((uchar*)xq + NP);              // n*128 bf16
    ushort* meanH = xh + NP;                              // n*128 bf16
    ushort* h1h = meanH + NP;                             // n*128 bf16
    ushort* WTfrag1 = h1h + NP;                           // 32768 ushorts each
    ushort* WTfrag2 = WTfrag1 + 32768;
    ushort* WoFrag  = WTfrag2 + 32768;                    // 8192 ushorts
    uchar* h1q = (uchar*)(WoFrag + 8192);                 // n*128 fp8 (12.8MB)

    hipMemsetAsync(bcnt, 0, sizeof(int) * 256, stream);
    bucket_cnt_kernel<<<(E + 8191) / 8192, 256, 0, stream>>>(ei, bcnt, E);
    bucket_scan_kernel<<<1, 256, 0, stream>>>(bcnt, boffs, bcur);
    binA_kernel<<<(E + NPB - 1) / NPB, 256, 0, stream>>>(ei, bcur, ebuf, E);
    binB2_kernel<<<NBUCK, 256, 0, stream>>>(ebuf, boffs, offs, csr, n);

    const int nxblk = (int)(NP / 8 / 256);    // 6250
    prep_kernel<<<nxblk + 36, 256, 0, stream>>>(x, xh, xq, W1l, W1r, W2l, W2r,
                                                Wout, WTfrag1, WTfrag2, WoFrag, nxblk);

    const int nblk = (n + 63) / 64;
    const int ablk = (n + 3) / 4;

    csr_agg8_kernel<<<ablk, 256, 0, stream>>>(xq, offs, csr, meanH, n);
    layer_mfma_kernel<false><<<nblk, 256, 0, stream>>>(
        meanH, xh, WTfrag1, b1, h1h, h1q,
        (const ushort*)nullptr, (const float*)nullptr, (float*)nullptr, n);

    csr_agg8_kernel<<<ablk, 256, 0, stream>>>((const uint*)h1q, offs, csr, meanH, n);
    layer_mfma_kernel<true><<<nblk, 256, 0, stream>>>(
        meanH, h1h, WTfrag2, b2, (ushort*)nullptr, (uchar*)nullptr,
        WoFrag, bout, out, n);
}

// Round 19
// 227.113 us; speedup vs baseline: 1.0308x; 1.0308x over previous
//
#include <hip/hip_runtime.h>
#include <hip/hip_fp8.h>

#define DD 128
#define CC 64
#define BKW 512            // nodes per bucket
#define NPB 4096           // edges per phase-B block

typedef __attribute__((ext_vector_type(8))) short short8v;
typedef __attribute__((ext_vector_type(4))) float f32x4;
typedef __attribute__((ext_vector_type(2))) float f32x2;

static __device__ inline ushort f2bf_rne(float f) {
    unsigned u = __float_as_uint(f);
    unsigned r = (u + 0x7FFFu + ((u >> 16) & 1u)) >> 16;
    return (ushort)r;
}
static __device__ inline float bf2f(ushort h) {
    return __uint_as_float(((unsigned)h) << 16);
}

// ============ bucket histogram: per-block LDS hist, 256 global atomics ======
__global__ __launch_bounds__(256) void bucket_cnt_kernel(const int* __restrict__ ei,
                                                         int* __restrict__ bcnt, int E) {
    __shared__ int h[256];
    const int t = threadIdx.x;
    h[t] = 0;
    __syncthreads();
    const int base = blockIdx.x * 8192;
    const int end = min(E, base + 8192);
    for (int j = base + t; j < end; j += 256) {
        atomicAdd(&h[ei[E + j] >> 9], 1);
    }
    __syncthreads();
    if (h[t]) atomicAdd(&bcnt[t], h[t]);
}

// ============ bucket scan (256 entries, 1 block) -> boffs[257], bcur ========
__global__ __launch_bounds__(256) void bucket_scan_kernel(const int* __restrict__ bcnt,
                                                          int* __restrict__ boffs,
                                                          int* __restrict__ bcur) {
    __shared__ int s[256];
    const int t = threadIdx.x;
    int v = bcnt[t];
    s[t] = v;
    __syncthreads();
    for (int off = 1; off < 256; off <<= 1) {
        int xv = 0;
        if (t >= off) xv = s[t - off];
        __syncthreads();
        if (t >= off) s[t] += xv;
        __syncthreads();
    }
    int excl = s[t] - v;
    boffs[t] = excl;
    bcur[t] = excl;
    if (t == 255) boffs[256] = s[255];
}

// ===== phase B: bin edges by bucket; packed word = src | (dst&511)<<17 ======
__global__ __launch_bounds__(256) void binA_kernel(const int* __restrict__ ei,
                                                   int* __restrict__ bcur,
                                                   uint* __restrict__ ebuf, int E) {
    __shared__ int sRun[256];
    __shared__ int sRel[256];
    __shared__ int sBase[256];
    __shared__ uint sPair[NPB];
    __shared__ unsigned char sBkt[NPB];
    __shared__ int sHist[256];
    const int t = threadIdx.x;
    const int e0 = blockIdx.x * NPB;
    const int cntE = min(NPB, E - e0);

    sHist[t] = 0;
    __syncthreads();
    for (int j = t; j < cntE; j += 256) {
        int dst = ei[E + e0 + j];
        atomicAdd(&sHist[dst >> 9], 1);
    }
    __syncthreads();
    int h = sHist[t];
    sRun[t] = h;
    __syncthreads();
    for (int off = 1; off < 256; off <<= 1) {
        int v = 0;
        if (t >= off) v = sRun[t - off];
        __syncthreads();
        if (t >= off) sRun[t] += v;
        __syncthreads();
    }
    int runstart = sRun[t] - h;
    int base = 0;
    if (h > 0) base = atomicAdd(&bcur[t], h);
    sRun[t] = runstart;
    sRel[t] = runstart;
    sBase[t] = base;
    __syncthreads();
    for (int j = t; j < cntE; j += 256) {
        int src = ei[e0 + j];
        int dst = ei[E + e0 + j];
        int b = dst >> 9;
        int slot = atomicAdd(&sRel[b], 1);
        sPair[slot] = (uint)src | ((uint)(dst & 511) << 17);
        sBkt[slot] = (unsigned char)b;
    }
    __syncthreads();
    for (int s = t; s < cntE; s += 256) {
        uint p = sPair[s];
        int b = (int)sBkt[s];
        int gpos = sBase[b] + (s - sRun[b]);
        ebuf[gpos] = p;
    }
}

// ====== phase C: per-bucket: derive per-node offs in LDS, then scatter =====
__global__ __launch_bounds__(256) void binB2_kernel(const uint* __restrict__ ebuf,
                                                    const int* __restrict__ boffs,
                                                    int* __restrict__ offs,
                                                    int* __restrict__ csr, int n) {
    __shared__ int sCnt[BKW];
    __shared__ int sOffs[BKW];
    __shared__ int sScan[256];
    const int t = threadIdx.x;
    const int node0 = blockIdx.x * BKW;
    const int node1 = min(n, node0 + BKW);
    const int start = boffs[blockIdx.x];
    const int end = boffs[blockIdx.x + 1];

    sCnt[t] = 0; sCnt[t + 256] = 0;
    __syncthreads();
    for (int j = start + t; j < end; j += 256) {
        int d = (int)(ebuf[j] >> 17);
        atomicAdd(&sCnt[d], 1);
    }
    __syncthreads();
    int v0 = sCnt[2 * t], v1 = sCnt[2 * t + 1];
    int sum = v0 + v1;
    sScan[t] = sum;
    __syncthreads();
    for (int off = 1; off < 256; off <<= 1) {
        int xv = 0;
        if (t >= off) xv = sScan[t - off];
        __syncthreads();
        if (t >= off) sScan[t] += xv;
        __syncthreads();
    }
    int excl = sScan[t] - sum;
    sOffs[2 * t] = start + excl;
    sOffs[2 * t + 1] = start + excl + v0;
    __syncthreads();
    for (int i = t; i < BKW; i += 256) {
        int node = node0 + i;
        if (node < n) offs[node] = sOffs[i];
    }
    if (node1 == n && t == 0) offs[n] = end;
    __syncthreads();
    sCnt[t] = 0; sCnt[t + 256] = 0;
    __syncthreads();
    for (int j = start + t; j < end; j += 256) {
        uint p = ebuf[j];
        int d = (int)(p >> 17);
        int r = atomicAdd(&sCnt[d], 1);
        csr[sOffs[d] + r] = (int)(p & 0x1FFFFu);
    }
}

// ===== merged prep: x -> (xh bf16, xq e4m3) + wfrag + wofrag ===============
__global__ __launch_bounds__(256) void prep_kernel(
    const float* __restrict__ x, ushort* __restrict__ xh, uint* __restrict__ xq,
    const float* __restrict__ Wl1, const float* __restrict__ Wr1,
    const float* __restrict__ Wl2, const float* __restrict__ Wr2,
    const float* __restrict__ Wout,
    ushort* __restrict__ WTfrag1, ushort* __restrict__ WTfrag2,
    ushort* __restrict__ WoFrag, int nxblk) {
    const int t = threadIdx.x;
    const int bx = blockIdx.x;
    if (bx < nxblk) {
        int i = bx * 256 + t;                    // 8 elems per thread
        float4 a = ((const float4*)x)[2 * i];
        float4 b = ((const float4*)x)[2 * i + 1];
        float vv[8] = {a.x, a.y, a.z, a.w, b.x, b.y, b.z, b.w};
        ushort r[8];
        uint q[8];
        #pragma unroll
        for (int j = 0; j < 8; ++j) {
            r[j] = f2bf_rne(vv[j]);
            q[j] = (uint)__hip_fp8_e4m3(vv[j]).__x;
        }
        uint4 o;
        o.x = (uint)r[0] | ((uint)r[1] << 16);
        o.y = (uint)r[2] | ((uint)r[3] << 16);
        o.z = (uint)r[4] | ((uint)r[5] << 16);
        o.w = (uint)r[6] | ((uint)r[7] << 16);
        ((uint4*)xh)[i] = o;
        uint2 oq;
        oq.x = q[0] | (q[1] << 8) | (q[2] << 16) | (q[3] << 24);
        oq.y = q[4] | (q[5] << 8) | (q[6] << 16) | (q[7] << 24);
        ((uint2*)xq)[i] = oq;
    } else if (bx < nxblk + 32) {
        int li = bx - nxblk;
        int layer = li >> 4;
        int idx = (li & 15) * 256 + t;           // [0, 4096)
        const float* Wl = layer ? Wl2 : Wl1;
        const float* Wr = layer ? Wr2 : Wr1;
        ushort* dst = (layer ? WTfrag2 : WTfrag1) + (size_t)idx * 8;
        int lane = idx & 63, tt = (idx >> 6) & 7, s = idx >> 9;
        int col = tt * 16 + (lane & 15);
        int k0 = s * 32 + (lane >> 4) * 8;
        #pragma unroll
        for (int j = 0; j < 8; ++j) {
            int k = k0 + j;
            float v = (k < DD) ? Wl[k * DD + col] : Wr[(k - DD) * DD + col];
            dst[j] = f2bf_rne(v);
        }
    } else {
        int idx = (bx - nxblk - 32) * 256 + t;   // [0, 1024)
        ushort* dst = WoFrag + (size_t)idx * 8;
        int lane = idx & 63, tt = (idx >> 6) & 3, kc = idx >> 8;
        int col = tt * 16 + (lane & 15);
        int k0 = kc * 32 + (lane >> 4) * 8;
        #pragma unroll
        for (int j = 0; j < 8; ++j) {
            dst[j] = f2bf_rne(Wout[(k0 + j) * CC + col]);
        }
    }
}

// ====== CSR gather-aggregate, fp8 rows: 16 nbrs in flight ====
__global__ __launch_bounds__(256) void csr_agg8_kernel(
    const uint* __restrict__ xq, const int* __restrict__ offs,
    const int* __restrict__ csr, ushort* __restrict__ meanH, int n) {
    int node = blockIdx.x * 4 + (threadIdx.x >> 6);
    if (node >= n) return;
    const int lane = threadIdx.x & 63;
    const int sub = lane >> 4;
    const int li = lane & 15;
    const int start = offs[node];
    const int c = offs[node + 1] - start;
    f32x2 a[4], aa[4];
    #pragma unroll
    for (int k = 0; k < 4; ++k) { a[k] = (f32x2){0.f, 0.f}; aa[k] = (f32x2){0.f, 0.f}; }
    #define ACC8(A, U) { \
        A[0] += __builtin_amdgcn_cvt_pk_f32_fp8(U.x, false); \
        A[1] += __builtin_amdgcn_cvt_pk_f32_fp8(U.x, true);  \
        A[2] += __builtin_amdgcn_cvt_pk_f32_fp8(U.y, false); \
        A[3] += __builtin_amdgcn_cvt_pk_f32_fp8(U.y, true);  }
    const int c16 = c & ~15;
    int j = 0;
    if (c16 > 0) {
        int s0 = csr[start + sub];
        int s1 = csr[start + 4 + sub];
        int s2 = csr[start + 8 + sub];
        int s3 = csr[start + 12 + sub];
        for (; j < c16; j += 16) {
            int t0 = 0, t1 = 0, t2 = 0, t3 = 0;
            if (j + 16 < c16) {
                t0 = csr[start + j + 16 + sub];
                t1 = csr[start + j + 20 + sub];
                t2 = csr[start + j + 24 + sub];
                t3 = csr[start + j + 28 + sub];
            }
            uint2 u0 = *(const uint2*)((const uchar*)xq + (size_t)s0 * DD + li * 8);
            uint2 u1 = *(const uint2*)((const uchar*)xq + (size_t)s1 * DD + li * 8);
            uint2 u2 = *(const uint2*)((const uchar*)xq + (size_t)s2 * DD + li * 8);
            uint2 u3 = *(const uint2*)((const uchar*)xq + (size_t)s3 * DD + li * 8);
            ACC8(a, u0); ACC8(a, u1); ACC8(aa, u2); ACC8(aa, u3);
            s0 = t0; s1 = t1; s2 = t2; s3 = t3;
        }
    }
    if (c - j >= 8) {
        int s0 = csr[start + j + sub];
        int s1 = csr[start + j + 4 + sub];
        uint2 u0 = *(const uint2*)((const uchar*)xq + (size_t)s0 * DD + li * 8);
        uint2 u1 = *(const uint2*)((const uchar*)xq + (size_t)s1 * DD + li * 8);
        ACC8(a, u0); ACC8(aa, u1);
        j += 8;
    }
    if (c - j >= 4) {
        int s = csr[start + j + sub];
        uint2 u = *(const uint2*)((const uchar*)xq + (size_t)s * DD + li * 8);
        ACC8(a, u);
        j += 4;
    }
    if (j + sub < c) {
        int s = csr[start + j + sub];
        uint2 u = *(const uint2*)((const uchar*)xq + (size_t)s * DD + li * 8);
        ACC8(aa, u);
    }
    #undef ACC8
    float res[8];
    #pragma unroll
    for (int k = 0; k < 4; ++k) {
        f32x2 v = a[k] + aa[k];
        float e0 = v.x; e0 += __shfl_xor(e0, 16); e0 += __shfl_xor(e0, 32);
        float e1 = v.y; e1 += __shfl_xor(e1, 16); e1 += __shfl_xor(e1, 32);
        res[2 * k] = e0; res[2 * k + 1] = e1;
    }
    if (sub == 0) {
        float inv = 1.0f / fmaxf((float)c, 1.0f);
        short8v o;
        #pragma unroll
        for (int k = 0; k < 8; ++k) o[k] = (short)f2bf_rne(res[k] * inv);
        *(short8v*)(meanH + (size_t)node * DD + li * 8) = o;
    }
}

// ===== MFMA SAGE layer: persistent-B registers, grid-stride 32-row tiles ====
// 4 waves = 2 row-halves x 2 col-halves. Each wave holds its 32 B-frags
// (128 VGPR) for the WHOLE kernel; K-loop = 8 A-loads + 32 MFMAs, no B traffic.
// Epilogue: LDS-staged, fully-coalesced uint4 row writes (fixes the 2.5x
// write amplification of scalar ushort/uchar stores seen in R18 counters).
template <bool PROJ>
__global__ __launch_bounds__(256) void layer_mfma_kernel(
    const ushort* __restrict__ meanH, const ushort* __restrict__ rootH,
    const ushort* __restrict__ WTfrag, const float* __restrict__ bias,
    ushort* __restrict__ outH, uchar* __restrict__ outQ,
    const ushort* __restrict__ WoFrag, const float* __restrict__ bout,
    float* __restrict__ outF, int n, int ntiles) {
    __shared__ ushort sH[32][136];
    __shared__ uchar sQ[PROJ ? 1 : 32][PROJ ? 16 : 144];
    const int tid = threadIdx.x;
    const int w = tid >> 6;
    const int l = tid & 63;
    const int rh = w >> 1;              // row-half 0/1
    const int ch = w & 1;               // col-half 0/1
    const int lrow = rh * 16 + (l & 15);
    const int kb = (l >> 4) * 8;
    const int lcol = l & 15;
    const int lrow0 = rh * 16 + (l >> 4) * 4;

    // persistent B: 32 frags = 128 VGPR (static indices via full unroll)
    short8v breg[8][4];
    #pragma unroll
    for (int s = 0; s < 8; ++s) {
        #pragma unroll
        for (int t = 0; t < 4; ++t) {
            breg[s][t] = *(const short8v*)(WTfrag + (size_t)s * 4096 +
                                           (ch * 4 + t) * 512 + l * 8);
        }
    }
    float bias_r[4];
    #pragma unroll
    for (int t = 0; t < 4; ++t) bias_r[t] = bias[ch * 64 + t * 16 + lcol];

    for (int tile = blockIdx.x; tile < ntiles; tile += gridDim.x) {
        const int row0 = tile * 32;
        const int arowg = min(row0 + lrow, n - 1);
        const ushort* Am = meanH + (size_t)arowg * DD;
        const ushort* Ar = rootH + (size_t)arowg * DD;
        short8v ap[8];
        #pragma unroll
        for (int s = 0; s < 8; ++s) {
            ap[s] = (s < 4) ? *(const short8v*)(Am + s * 32 + kb)
                            : *(const short8v*)(Ar + (s - 4) * 32 + kb);
        }
        f32x4 acc[4];
        #pragma unroll
        for (int t = 0; t < 4; ++t) acc[t] = (f32x4){0.f, 0.f, 0.f, 0.f};
        #pragma unroll
        for (int s = 0; s < 8; ++s) {
            #pragma unroll
            for (int t = 0; t < 4; ++t) {
                acc[t] = __builtin_amdgcn_mfma_f32_16x16x32_bf16(ap[s], breg[s][t],
                                                                 acc[t], 0, 0, 0);
            }
        }

        if (!PROJ) {
            // stage bf16 + fp8 (disjoint regions per wave), then coalesced write
            #pragma unroll
            for (int t = 0; t < 4; ++t) {
                const int col = ch * 64 + t * 16 + lcol;
                #pragma unroll
                for (int r = 0; r < 4; ++r) {
                    float o = fmaxf(acc[t][r] + bias_r[t], 0.f);
                    sH[lrow0 + r][col] = f2bf_rne(o);
                    sQ[lrow0 + r][col] = __hip_fp8_e4m3(o).__x;
                }
            }
            __syncthreads();
            for (int i = tid; i < 512; i += 256) {     // 32 rows x 16 segs x 16B
                int row = i >> 4, seg = i & 15;
                int grow = row0 + row;
                if (grow < n)
                    *(uint4*)(outH + (size_t)grow * DD + seg * 8) =
                        *(const uint4*)&sH[row][seg * 8];
            }
            {
                int row = tid >> 3, seg = tid & 7;     // 32 rows x 8 segs x 16B
                int grow = row0 + row;
                if (grow < n)
                    *(uint4*)(outQ + (size_t)grow * DD + seg * 16) =
                        *(const uint4*)&sQ[row][seg * 16];
            }
            __syncthreads();
        } else {
            #pragma unroll
            for (int t = 0; t < 4; ++t) {
                const int col = ch * 64 + t * 16 + lcol;
                #pragma unroll
                for (int r = 0; r < 4; ++r) {
                    sH[lrow0 + r][col] = f2bf_rne(fmaxf(acc[t][r] + bias_r[t], 0.f));
                }
            }
            __syncthreads();
            f32x4 po[2];
            po[0] = (f32x4){0.f, 0.f, 0.f, 0.f};
            po[1] = (f32x4){0.f, 0.f, 0.f, 0.f};
            #pragma unroll
            for (int kc = 0; kc < 4; ++kc) {
                short8v ah = *(const short8v*)&sH[lrow][kc * 32 + kb];
                #pragma unroll
                for (int t2 = 0; t2 < 2; ++t2) {
                    short8v bh = *(const short8v*)(WoFrag + (size_t)kc * 2048 +
                                                   (ch * 2 + t2) * 512 + l * 8);
                    po[t2] = __builtin_amdgcn_mfma_f32_16x16x32_bf16(ah, bh,
                                                                     po[t2], 0, 0, 0);
                }
            }
            #pragma unroll
            for (int t2 = 0; t2 < 2; ++t2) {
                const int col = ch * 32 + t2 * 16 + lcol;
                const float b = bout[col];
                #pragma unroll
                for (int r = 0; r < 4; ++r) {
                    int grow = row0 + lrow0 + r;
                    if (grow < n) outF[(size_t)grow * CC + col] = po[t2][r] + b;
                }
            }
            __syncthreads();
        }
    }
}

extern "C" void kernel_launch(void* const* d_in, const int* in_sizes, int n_in,
                              void* d_out, int out_size, void* d_ws, size_t ws_size,
                              hipStream_t stream) {
    const float* x    = (const float*)d_in[0];
    const int*   ei   = (const int*)d_in[1];
    const float* W1l  = (const float*)d_in[2];
    const float* b1   = (const float*)d_in[3];
    const float* W1r  = (const float*)d_in[4];
    const float* W2l  = (const float*)d_in[5];
    const float* b2   = (const float*)d_in[6];
    const float* W2r  = (const float*)d_in[7];
    const float* Wout = (const float*)d_in[8];
    const float* bout = (const float*)d_in[9];
    float* out = (float*)d_out;
    const int n = in_sizes[0] / DD;       // 100000
    const int E = in_sizes[1] / 2;        // 1600000
    const size_t NP = (size_t)n * DD;

    const int NBUCK = (n + BKW - 1) / BKW;

    // workspace (~110 MB); ebuf (6.4MB) aliases the front of xq (12.8MB):
    // ebuf is dead after binB2; prep (which writes xq) runs after binB2.
    int* offs  = (int*)d_ws;                              // 100352 (incl offs[n])
    int* bcnt  = offs + 100352;                           // 256
    int* boffs = bcnt + 256;                              // 257 (pad 512)
    int* bcur  = boffs + 512;                             // 256
    int* csr   = bcur + 256;                              // E (pad)
    uint* ebuf = (uint*)(csr + 1600256);                  // E packed words
    uint* xq   = ebuf;                                    // n*128 fp8 (12.8MB)
    ushort* xh = (ushort*)((uchar*)xq + NP);              // n*128 bf16
    ushort* meanH = xh + NP;                              // n*128 bf16
    ushort* h1h = meanH + NP;                             // n*128 bf16
    ushort* WTfrag1 = h1h + NP;                           // 32768 ushorts each
    ushort* WTfrag2 = WTfrag1 + 32768;
    ushort* WoFrag  = WTfrag2 + 32768;                    // 8192 ushorts
    uchar* h1q = (uchar*)(WoFrag + 8192);                 // n*128 fp8 (12.8MB)

    hipMemsetAsync(bcnt, 0, sizeof(int) * 256, stream);
    bucket_cnt_kernel<<<(E + 8191) / 8192, 256, 0, stream>>>(ei, bcnt, E);
    bucket_scan_kernel<<<1, 256, 0, stream>>>(bcnt, boffs, bcur);
    binA_kernel<<<(E + NPB - 1) / NPB, 256, 0, stream>>>(ei, bcur, ebuf, E);
    binB2_kernel<<<NBUCK, 256, 0, stream>>>(ebuf, boffs, offs, csr, n);

    const int nxblk = (int)(NP / 8 / 256);    // 6250
    prep_kernel<<<nxblk + 36, 256, 0, stream>>>(x, xh, xq, W1l, W1r, W2l, W2r,
                                                Wout, WTfrag1, WTfrag2, WoFrag, nxblk);

    const int ntiles = (n + 31) / 32;         // 3125
    const int lgrid = 625;                    // 5 tiles per block
    const int ablk = (n + 3) / 4;

    csr_agg8_kernel<<<ablk, 256, 0, stream>>>(xq, offs, csr, meanH, n);
    layer_mfma_kernel<false><<<lgrid, 256, 0, stream>>>(
        meanH, xh, WTfrag1, b1, h1h, h1q,
        (const ushort*)nullptr, (const float*)nullptr, (float*)nullptr, n, ntiles);

    csr_agg8_kernel<<<ablk, 256, 0, stream>>>((const uint*)h1q, offs, csr, meanH, n);
    layer_mfma_kernel<true><<<lgrid, 256, 0, stream>>>(
        meanH, h1h, WTfrag2, b2, (ushort*)nullptr, (uchar*)nullptr,
        WoFrag, bout, out, n, ntiles);
}

// Round 20
// 220.026 us; speedup vs baseline: 1.0640x; 1.0322x over previous
//
#include <hip/hip_runtime.h>
#include <hip/hip_fp8.h>

#define DD 128
#define CC 64
#define BKW 512            // nodes per bucket
#define NPB 4096           // edges per phase-B block

typedef __attribute__((ext_vector_type(8))) short short8v;
typedef __attribute__((ext_vector_type(4))) float f32x4;
typedef __attribute__((ext_vector_type(2))) float f32x2;

static __device__ inline ushort f2bf_rne(float f) {
    unsigned u = __float_as_uint(f);
    unsigned r = (u + 0x7FFFu + ((u >> 16) & 1u)) >> 16;
    return (ushort)r;
}
static __device__ inline float bf2f(ushort h) {
    return __uint_as_float(((unsigned)h) << 16);
}

// ============ bucket histogram: per-block LDS hist, 256 global atomics ======
__global__ __launch_bounds__(256) void bucket_cnt_kernel(const int* __restrict__ ei,
                                                         int* __restrict__ bcnt, int E) {
    __shared__ int h[256];
    const int t = threadIdx.x;
    h[t] = 0;
    __syncthreads();
    const int base = blockIdx.x * 8192;
    const int end = min(E, base + 8192);
    for (int j = base + t; j < end; j += 256) {
        atomicAdd(&h[ei[E + j] >> 9], 1);
    }
    __syncthreads();
    if (h[t]) atomicAdd(&bcnt[t], h[t]);
}

// ============ bucket scan (256 entries, 1 block) -> boffs[257], bcur ========
__global__ __launch_bounds__(256) void bucket_scan_kernel(const int* __restrict__ bcnt,
                                                          int* __restrict__ boffs,
                                                          int* __restrict__ bcur) {
    __shared__ int s[256];
    const int t = threadIdx.x;
    int v = bcnt[t];
    s[t] = v;
    __syncthreads();
    for (int off = 1; off < 256; off <<= 1) {
        int xv = 0;
        if (t >= off) xv = s[t - off];
        __syncthreads();
        if (t >= off) s[t] += xv;
        __syncthreads();
    }
    int excl = s[t] - v;
    boffs[t] = excl;
    bcur[t] = excl;
    if (t == 255) boffs[256] = s[255];
}

// ===== phase B: bin edges by bucket; packed word = src | (dst&511)<<17 ======
__global__ __launch_bounds__(256) void binA_kernel(const int* __restrict__ ei,
                                                   int* __restrict__ bcur,
                                                   uint* __restrict__ ebuf, int E) {
    __shared__ int sRun[256];
    __shared__ int sRel[256];
    __shared__ int sBase[256];
    __shared__ uint sPair[NPB];
    __shared__ unsigned char sBkt[NPB];
    __shared__ int sHist[256];
    const int t = threadIdx.x;
    const int e0 = blockIdx.x * NPB;
    const int cntE = min(NPB, E - e0);

    sHist[t] = 0;
    __syncthreads();
    for (int j = t; j < cntE; j += 256) {
        int dst = ei[E + e0 + j];
        atomicAdd(&sHist[dst >> 9], 1);
    }
    __syncthreads();
    int h = sHist[t];
    sRun[t] = h;
    __syncthreads();
    for (int off = 1; off < 256; off <<= 1) {
        int v = 0;
        if (t >= off) v = sRun[t - off];
        __syncthreads();
        if (t >= off) sRun[t] += v;
        __syncthreads();
    }
    int runstart = sRun[t] - h;
    int base = 0;
    if (h > 0) base = atomicAdd(&bcur[t], h);
    sRun[t] = runstart;
    sRel[t] = runstart;
    sBase[t] = base;
    __syncthreads();
    for (int j = t; j < cntE; j += 256) {
        int src = ei[e0 + j];
        int dst = ei[E + e0 + j];
        int b = dst >> 9;
        int slot = atomicAdd(&sRel[b], 1);
        sPair[slot] = (uint)src | ((uint)(dst & 511) << 17);
        sBkt[slot] = (unsigned char)b;
    }
    __syncthreads();
    for (int s = t; s < cntE; s += 256) {
        uint p = sPair[s];
        int b = (int)sBkt[s];
        int gpos = sBase[b] + (s - sRun[b]);
        ebuf[gpos] = p;
    }
}

// ====== phase C: per-bucket: derive per-node offs in LDS, then scatter =====
__global__ __launch_bounds__(256) void binB2_kernel(const uint* __restrict__ ebuf,
                                                    const int* __restrict__ boffs,
                                                    int* __restrict__ offs,
                                                    int* __restrict__ csr, int n) {
    __shared__ int sCnt[BKW];
    __shared__ int sOffs[BKW];
    __shared__ int sScan[256];
    const int t = threadIdx.x;
    const int node0 = blockIdx.x * BKW;
    const int node1 = min(n, node0 + BKW);
    const int start = boffs[blockIdx.x];
    const int end = boffs[blockIdx.x + 1];

    sCnt[t] = 0; sCnt[t + 256] = 0;
    __syncthreads();
    for (int j = start + t; j < end; j += 256) {
        int d = (int)(ebuf[j] >> 17);
        atomicAdd(&sCnt[d], 1);
    }
    __syncthreads();
    int v0 = sCnt[2 * t], v1 = sCnt[2 * t + 1];
    int sum = v0 + v1;
    sScan[t] = sum;
    __syncthreads();
    for (int off = 1; off < 256; off <<= 1) {
        int xv = 0;
        if (t >= off) xv = sScan[t - off];
        __syncthreads();
        if (t >= off) sScan[t] += xv;
        __syncthreads();
    }
    int excl = sScan[t] - sum;
    sOffs[2 * t] = start + excl;
    sOffs[2 * t + 1] = start + excl + v0;
    __syncthreads();
    for (int i = t; i < BKW; i += 256) {
        int node = node0 + i;
        if (node < n) offs[node] = sOffs[i];
    }
    if (node1 == n && t == 0) offs[n] = end;
    __syncthreads();
    sCnt[t] = 0; sCnt[t + 256] = 0;
    __syncthreads();
    for (int j = start + t; j < end; j += 256) {
        uint p = ebuf[j];
        int d = (int)(p >> 17);
        int r = atomicAdd(&sCnt[d], 1);
        csr[sOffs[d] + r] = (int)(p & 0x1FFFFu);
    }
}

// ===== merged prep: x -> (xh bf16, xq e4m3) + wfrag + wofrag ===============
__global__ __launch_bounds__(256) void prep_kernel(
    const float* __restrict__ x, ushort* __restrict__ xh, uint* __restrict__ xq,
    const float* __restrict__ Wl1, const float* __restrict__ Wr1,
    const float* __restrict__ Wl2, const float* __restrict__ Wr2,
    const float* __restrict__ Wout,
    ushort* __restrict__ WTfrag1, ushort* __restrict__ WTfrag2,
    ushort* __restrict__ WoFrag, int nxblk) {
    const int t = threadIdx.x;
    const int bx = blockIdx.x;
    if (bx < nxblk) {
        int i = bx * 256 + t;                    // 8 elems per thread
        float4 a = ((const float4*)x)[2 * i];
        float4 b = ((const float4*)x)[2 * i + 1];
        float vv[8] = {a.x, a.y, a.z, a.w, b.x, b.y, b.z, b.w};
        ushort r[8];
        uint q[8];
        #pragma unroll
        for (int j = 0; j < 8; ++j) {
            r[j] = f2bf_rne(vv[j]);
            q[j] = (uint)__hip_fp8_e4m3(vv[j]).__x;
        }
        uint4 o;
        o.x = (uint)r[0] | ((uint)r[1] << 16);
        o.y = (uint)r[2] | ((uint)r[3] << 16);
        o.z = (uint)r[4] | ((uint)r[5] << 16);
        o.w = (uint)r[6] | ((uint)r[7] << 16);
        ((uint4*)xh)[i] = o;
        uint2 oq;
        oq.x = q[0] | (q[1] << 8) | (q[2] << 16) | (q[3] << 24);
        oq.y = q[4] | (q[5] << 8) | (q[6] << 16) | (q[7] << 24);
        ((uint2*)xq)[i] = oq;
    } else if (bx < nxblk + 32) {
        int li = bx - nxblk;
        int layer = li >> 4;
        int idx = (li & 15) * 256 + t;           // [0, 4096)
        const float* Wl = layer ? Wl2 : Wl1;
        const float* Wr = layer ? Wr2 : Wr1;
        ushort* dst = (layer ? WTfrag2 : WTfrag1) + (size_t)idx * 8;
        int lane = idx & 63, tt = (idx >> 6) & 7, s = idx >> 9;
        int col = tt * 16 + (lane & 15);
        int k0 = s * 32 + (lane >> 4) * 8;
        #pragma unroll
        for (int j = 0; j < 8; ++j) {
            int k = k0 + j;
            float v = (k < DD) ? Wl[k * DD + col] : Wr[(k - DD) * DD + col];
            dst[j] = f2bf_rne(v);
        }
    } else {
        int idx = (bx - nxblk - 32) * 256 + t;   // [0, 1024)
        ushort* dst = WoFrag + (size_t)idx * 8;
        int lane = idx & 63, tt = (idx >> 6) & 3, kc = idx >> 8;
        int col = tt * 16 + (lane & 15);
        int k0 = kc * 32 + (lane >> 4) * 8;
        #pragma unroll
        for (int j = 0; j < 8; ++j) {
            dst[j] = f2bf_rne(Wout[(k0 + j) * CC + col]);
        }
    }
}

// ====== CSR gather-aggregate, fp8 rows: 16 nbrs in flight ====
__global__ __launch_bounds__(256) void csr_agg8_kernel(
    const uint* __restrict__ xq, const int* __restrict__ offs,
    const int* __restrict__ csr, ushort* __restrict__ meanH, int n) {
    int node = blockIdx.x * 4 + (threadIdx.x >> 6);
    if (node >= n) return;
    const int lane = threadIdx.x & 63;
    const int sub = lane >> 4;
    const int li = lane & 15;
    const int start = offs[node];
    const int c = offs[node + 1] - start;
    f32x2 a[4], aa[4];
    #pragma unroll
    for (int k = 0; k < 4; ++k) { a[k] = (f32x2){0.f, 0.f}; aa[k] = (f32x2){0.f, 0.f}; }
    #define ACC8(A, U) { \
        A[0] += __builtin_amdgcn_cvt_pk_f32_fp8(U.x, false); \
        A[1] += __builtin_amdgcn_cvt_pk_f32_fp8(U.x, true);  \
        A[2] += __builtin_amdgcn_cvt_pk_f32_fp8(U.y, false); \
        A[3] += __builtin_amdgcn_cvt_pk_f32_fp8(U.y, true);  }
    const int c16 = c & ~15;
    int j = 0;
    if (c16 > 0) {
        int s0 = csr[start + sub];
        int s1 = csr[start + 4 + sub];
        int s2 = csr[start + 8 + sub];
        int s3 = csr[start + 12 + sub];
        for (; j < c16; j += 16) {
            int t0 = 0, t1 = 0, t2 = 0, t3 = 0;
            if (j + 16 < c16) {
                t0 = csr[start + j + 16 + sub];
                t1 = csr[start + j + 20 + sub];
                t2 = csr[start + j + 24 + sub];
                t3 = csr[start + j + 28 + sub];
            }
            uint2 u0 = *(const uint2*)((const uchar*)xq + (size_t)s0 * DD + li * 8);
            uint2 u1 = *(const uint2*)((const uchar*)xq + (size_t)s1 * DD + li * 8);
            uint2 u2 = *(const uint2*)((const uchar*)xq + (size_t)s2 * DD + li * 8);
            uint2 u3 = *(const uint2*)((const uchar*)xq + (size_t)s3 * DD + li * 8);
            ACC8(a, u0); ACC8(a, u1); ACC8(aa, u2); ACC8(aa, u3);
            s0 = t0; s1 = t1; s2 = t2; s3 = t3;
        }
    }
    if (c - j >= 8) {
        int s0 = csr[start + j + sub];
        int s1 = csr[start + j + 4 + sub];
        uint2 u0 = *(const uint2*)((const uchar*)xq + (size_t)s0 * DD + li * 8);
        uint2 u1 = *(const uint2*)((const uchar*)xq + (size_t)s1 * DD + li * 8);
        ACC8(a, u0); ACC8(aa, u1);
        j += 8;
    }
    if (c - j >= 4) {
        int s = csr[start + j + sub];
        uint2 u = *(const uint2*)((const uchar*)xq + (size_t)s * DD + li * 8);
        ACC8(a, u);
        j += 4;
    }
    if (j + sub < c) {
        int s = csr[start + j + sub];
        uint2 u = *(const uint2*)((const uchar*)xq + (size_t)s * DD + li * 8);
        ACC8(aa, u);
    }
    #undef ACC8
    float res[8];
    #pragma unroll
    for (int k = 0; k < 4; ++k) {
        f32x2 v = a[k] + aa[k];
        float e0 = v.x; e0 += __shfl_xor(e0, 16); e0 += __shfl_xor(e0, 32);
        float e1 = v.y; e1 += __shfl_xor(e1, 16); e1 += __shfl_xor(e1, 32);
        res[2 * k] = e0; res[2 * k + 1] = e1;
    }
    if (sub == 0) {
        float inv = 1.0f / fmaxf((float)c, 1.0f);
        short8v o;
        #pragma unroll
        for (int k = 0; k < 8; ++k) o[k] = (short)f2bf_rne(res[k] * inv);
        *(short8v*)(meanH + (size_t)node * DD + li * 8) = o;
    }
}

// ===== MFMA SAGE layer: 16-row tiles, wave = col-quarter (B in 64 VGPR) =====
// 4 waves x (16 rows x 32 cols). Per tile/wave: 8 A-loads + 16 MFMAs.
// !PROJ: wave-LOCAL LDS restage (no barriers at all) -> coalesced uint4 writes.
// PROJ: one barrier + ping-pong sH (barrier-drift safe), 4 proj MFMAs/wave.
template <bool PROJ>
__global__ __launch_bounds__(256) void layer_mfma_kernel(
    const ushort* __restrict__ meanH, const ushort* __restrict__ rootH,
    const ushort* __restrict__ WTfrag, const float* __restrict__ bias,
    ushort* __restrict__ outH, uchar* __restrict__ outQ,
    const ushort* __restrict__ WoFrag, const float* __restrict__ bout,
    float* __restrict__ outF, int n, int ntiles) {
    __shared__ ushort sW[PROJ ? 1 : 4][16][40];          // wave-local bf16 stage
    __shared__ __align__(16) uchar sQ[PROJ ? 1 : 4][16][48];  // wave-local fp8 stage
    __shared__ ushort sH[PROJ ? 2 : 1][16][136];         // PROJ ping-pong h2
    const int tid = threadIdx.x;
    const int w = tid >> 6;             // col-quarter
    const int l = tid & 63;
    const int lrow16 = l & 15;          // A row within tile
    const int kb = (l >> 4) * 8;
    const int lcol = l & 15;
    const int lrow0 = (l >> 4) * 4;     // C rows within tile

    // persistent B: 16 frags (cols w*32 .. w*32+31) = 64 VGPR
    short8v breg[8][2];
    #pragma unroll
    for (int s = 0; s < 8; ++s) {
        #pragma unroll
        for (int t = 0; t < 2; ++t) {
            breg[s][t] = *(const short8v*)(WTfrag + (size_t)s * 4096 +
                                           (w * 2 + t) * 512 + l * 8);
        }
    }
    float bias_r[2];
    #pragma unroll
    for (int t = 0; t < 2; ++t) bias_r[t] = bias[w * 32 + t * 16 + lcol];

    int pp = 0;
    for (int tile = blockIdx.x; tile < ntiles; tile += gridDim.x, pp ^= 1) {
        const int row0 = tile * 16;
        const int arowg = min(row0 + lrow16, n - 1);
        const ushort* Am = meanH + (size_t)arowg * DD;
        const ushort* Ar = rootH + (size_t)arowg * DD;
        short8v ap[8];
        #pragma unroll
        for (int s = 0; s < 8; ++s) {
            ap[s] = (s < 4) ? *(const short8v*)(Am + s * 32 + kb)
                            : *(const short8v*)(Ar + (s - 4) * 32 + kb);
        }
        f32x4 acc[2];
        acc[0] = (f32x4){0.f, 0.f, 0.f, 0.f};
        acc[1] = (f32x4){0.f, 0.f, 0.f, 0.f};
        #pragma unroll
        for (int s = 0; s < 8; ++s) {
            acc[0] = __builtin_amdgcn_mfma_f32_16x16x32_bf16(ap[s], breg[s][0],
                                                             acc[0], 0, 0, 0);
            acc[1] = __builtin_amdgcn_mfma_f32_16x16x32_bf16(ap[s], breg[s][1],
                                                             acc[1], 0, 0, 0);
        }

        if (!PROJ) {
            // stage (wave-local; same-wave LDS ordering, no barrier needed)
            #pragma unroll
            for (int t = 0; t < 2; ++t) {
                #pragma unroll
                for (int r = 0; r < 4; ++r) {
                    float o = fmaxf(acc[t][r] + bias_r[t], 0.f);
                    sW[w][lrow0 + r][t * 16 + lcol] = f2bf_rne(o);
                    sQ[w][lrow0 + r][t * 16 + lcol] = __hip_fp8_e4m3(o).__x;
                }
            }
            // coalesced store: bf16 16 rows x 4 segs x 16B
            {
                int row = l >> 2, seg = l & 3;
                int grow = row0 + row;
                if (grow < n)
                    *(uint4*)(outH + (size_t)grow * DD + w * 32 + seg * 8) =
                        *(const uint4*)&sW[w][row][seg * 8];
            }
            // fp8: 16 rows x 2 segs x 16B (lanes 0..31)
            if (l < 32) {
                int row = l >> 1, seg = l & 1;
                int grow = row0 + row;
                if (grow < n)
                    *(uint4*)(outQ + (size_t)grow * DD + w * 32 + seg * 16) =
                        *(const uint4*)&sQ[w][row][seg * 16];
            }
        } else {
            #pragma unroll
            for (int t = 0; t < 2; ++t) {
                #pragma unroll
                for (int r = 0; r < 4; ++r) {
                    sH[pp][lrow0 + r][w * 32 + t * 16 + lcol] =
                        f2bf_rne(fmaxf(acc[t][r] + bias_r[t], 0.f));
                }
            }
            __syncthreads();
            f32x4 po = (f32x4){0.f, 0.f, 0.f, 0.f};
            #pragma unroll
            for (int kc = 0; kc < 4; ++kc) {
                short8v ah = *(const short8v*)&sH[pp][lrow16][kc * 32 + kb];
                short8v bh = *(const short8v*)(WoFrag + (size_t)kc * 2048 +
                                               w * 512 + l * 8);
                po = __builtin_amdgcn_mfma_f32_16x16x32_bf16(ah, bh, po, 0, 0, 0);
            }
            const int col = w * 16 + lcol;
            const float b = bout[col];
            #pragma unroll
            for (int r = 0; r < 4; ++r) {
                int grow = row0 + lrow0 + r;
                if (grow < n) outF[(size_t)grow * CC + col] = po[r] + b;
            }
        }
    }
}

extern "C" void kernel_launch(void* const* d_in, const int* in_sizes, int n_in,
                              void* d_out, int out_size, void* d_ws, size_t ws_size,
                              hipStream_t stream) {
    const float* x    = (const float*)d_in[0];
    const int*   ei   = (const int*)d_in[1];
    const float* W1l  = (const float*)d_in[2];
    const float* b1   = (const float*)d_in[3];
    const float* W1r  = (const float*)d_in[4];
    const float* W2l  = (const float*)d_in[5];
    const float* b2   = (const float*)d_in[6];
    const float* W2r  = (const float*)d_in[7];
    const float* Wout = (const float*)d_in[8];
    const float* bout = (const float*)d_in[9];
    float* out = (float*)d_out;
    const int n = in_sizes[0] / DD;       // 100000
    const int E = in_sizes[1] / 2;        // 1600000
    const size_t NP = (size_t)n * DD;

    const int NBUCK = (n + BKW - 1) / BKW;

    // workspace (~110 MB); ebuf (6.4MB) aliases the front of xq (12.8MB):
    // ebuf is dead after binB2; prep (which writes xq) runs after binB2.
    int* offs  = (int*)d_ws;                              // 100352 (incl offs[n])
    int* bcnt  = offs + 100352;                           // 256
    int* boffs = bcnt + 256;                              // 257 (pad 512)
    int* bcur  = boffs + 512;                             // 256
    int* csr   = bcur + 256;                              // E (pad)
    uint* ebuf = (uint*)(csr + 1600256);                  // E packed words
    uint* xq   = ebuf;                                    // n*128 fp8 (12.8MB)
    ushort* xh = (ushort*)((uchar*)xq + NP);              // n*128 bf16
    ushort* meanH = xh + NP;                              // n*128 bf16
    ushort* h1h = meanH + NP;                             // n*128 bf16
    ushort* WTfrag1 = h1h + NP;                           // 32768 ushorts each
    ushort* WTfrag2 = WTfrag1 + 32768;
    ushort* WoFrag  = WTfrag2 + 32768;                    // 8192 ushorts
    uchar* h1q = (uchar*)(WoFrag + 8192);                 // n*128 fp8 (12.8MB)

    hipMemsetAsync(bcnt, 0, sizeof(int) * 256, stream);
    bucket_cnt_kernel<<<(E + 8191) / 8192, 256, 0, stream>>>(ei, bcnt, E);
    bucket_scan_kernel<<<1, 256, 0, stream>>>(bcnt, boffs, bcur);
    binA_kernel<<<(E + NPB - 1) / NPB, 256, 0, stream>>>(ei, bcur, ebuf, E);
    binB2_kernel<<<NBUCK, 256, 0, stream>>>(ebuf, boffs, offs, csr, n);

    const int nxblk = (int)(NP / 8 / 256);    // 6250
    prep_kernel<<<nxblk + 36, 256, 0, stream>>>(x, xh, xq, W1l, W1r, W2l, W2r,
                                                Wout, WTfrag1, WTfrag2, WoFrag, nxblk);

    const int ntiles = (n + 15) / 16;         // 6250
    const int lgrid = 1024;
    const int ablk = (n + 3) / 4;

    csr_agg8_kernel<<<ablk, 256, 0, stream>>>(xq, offs, csr, meanH, n);
    layer_mfma_kernel<false><<<lgrid, 256, 0, stream>>>(
        meanH, xh, WTfrag1, b1, h1h, h1q,
        (const ushort*)nullptr, (const float*)nullptr, (float*)nullptr, n, ntiles);

    csr_agg8_kernel<<<ablk, 256, 0, stream>>>((const uint*)h1q, offs, csr, meanH, n);
    layer_mfma_kernel<true><<<lgrid, 256, 0, stream>>>(
        meanH, h1h, WTfrag2, b2, (ushort*)nullptr, (uchar*)nullptr,
        WoFrag, bout, out, n, ntiles);
}